// Round 1
// baseline (172.233 us; speedup 1.0000x reference)
//
#include <hip/hip_runtime.h>
#include <stdint.h>

#define IN_DIM 4096
#define H_DIM  2048
#define NPTS   2097152

typedef short  bf16x8  __attribute__((ext_vector_type(8)));
typedef float  floatx4 __attribute__((ext_vector_type(4)));

__device__ __forceinline__ unsigned short f2bf(float f) {
    unsigned u = __float_as_uint(f);
    unsigned r = (u + 0x7FFFu + ((u >> 16) & 1u)) >> 16;   // RNE
    return (unsigned short)r;
}

// ---------------- Kernel 1: h = bf16(tanh(W1 + b1)) ----------------
__global__ void prep_h(const float* __restrict__ W1, const float* __restrict__ b1,
                       unsigned short* __restrict__ hbf) {
    int idx = (blockIdx.x * 256 + threadIdx.x) * 4;           // 8192 blocks cover 8388608
    float4 w = *(const float4*)(W1 + idx);
    float4 b = *(const float4*)(b1 + (idx & (H_DIM - 1)));
    ushort4 o;
    o.x = f2bf(tanhf(w.x + b.x));
    o.y = f2bf(tanhf(w.y + b.y));
    o.z = f2bf(tanhf(w.z + b.z));
    o.w = f2bf(tanhf(w.w + b.w));
    *(ushort4*)(hbf + idx) = o;
}

// ---------------- Kernel 2: W2T = bf16(W2^T), 64x64 LDS tiles ----------------
__global__ void prep_w2t(const float* __restrict__ W2, unsigned short* __restrict__ W2T) {
    __shared__ unsigned short tile[64][66];
    int k0 = blockIdx.y * 64, n0 = blockIdx.x * 64;
    for (int idx = threadIdx.x; idx < 64 * 64; idx += 256) {
        int r = idx >> 6, c = idx & 63;                 // c fast -> coalesced read of W2 row
        tile[c][r] = f2bf(W2[(size_t)(k0 + r) * H_DIM + n0 + c]);
    }
    __syncthreads();
    for (int idx = threadIdx.x; idx < 64 * 64; idx += 256) {
        int r = idx >> 6, c = idx & 63;                 // c fast -> coalesced write of W2T row
        W2T[(size_t)(n0 + r) * H_DIM + k0 + c] = tile[r][c];
    }
}

// ---------------- Kernel 3: fused GEMM + tanh + @W3 row-reduce ----------------
// C[m,n] = sum_k A[m,k]*B[k,n];  rowsum[m] += sum_n tanh(C[m,n]+b2[n])*W3[n]
#define BK 32
__global__ __launch_bounds__(256, 2) void gemm_fused(
    const unsigned short* __restrict__ A,    // 4096 x 2048 bf16 (h)
    const unsigned short* __restrict__ BT,   // 2048 x 2048 bf16 (W2^T, N x K)
    const float* __restrict__ b2, const float* __restrict__ W3,
    float* __restrict__ rowsum) {
    __shared__ __align__(16) unsigned short As[128 * BK];   // 8 KB
    __shared__ __align__(16) unsigned short Bs[128 * BK];   // 8 KB
    const int K = H_DIM;
    const int t = threadIdx.x;
    const int w = t >> 6, l = t & 63;
    const int lane16 = l & 15, quad = l >> 4;
    const int wr = w >> 1, wc = w & 1;                      // 2x2 waves over 128x128
    const int rowBase = blockIdx.y * 128;
    const int colBase = blockIdx.x * 128;

    // staging: thread t loads 8 contiguous bf16 (16B); row = issue*64 + t/4, kcol = (t&3)*8
    const unsigned short* aSrc = A  + (size_t)(rowBase + (t >> 2)) * K + (t & 3) * 8;
    const unsigned short* bSrc = BT + (size_t)(colBase + (t >> 2)) * K + (t & 3) * 8;
    unsigned short* aDst = As + (w << 9);                   // wave-uniform LDS base (elements)
    unsigned short* bDst = Bs + (w << 9);

    floatx4 acc[4][4];
    floatx4 zero = {0.f, 0.f, 0.f, 0.f};
#pragma unroll
    for (int i = 0; i < 4; ++i)
#pragma unroll
        for (int j = 0; j < 4; ++j) acc[i][j] = zero;

    for (int k0 = 0; k0 < K; k0 += BK) {
        __syncthreads();
        __builtin_amdgcn_global_load_lds(
            (const __attribute__((address_space(1))) void*)(aSrc + k0),
            (__attribute__((address_space(3))) void*)aDst, 16, 0, 0);
        __builtin_amdgcn_global_load_lds(
            (const __attribute__((address_space(1))) void*)(aSrc + (size_t)64 * K + k0),
            (__attribute__((address_space(3))) void*)(aDst + 2048), 16, 0, 0);
        __builtin_amdgcn_global_load_lds(
            (const __attribute__((address_space(1))) void*)(bSrc + k0),
            (__attribute__((address_space(3))) void*)bDst, 16, 0, 0);
        __builtin_amdgcn_global_load_lds(
            (const __attribute__((address_space(1))) void*)(bSrc + (size_t)64 * K + k0),
            (__attribute__((address_space(3))) void*)(bDst + 2048), 16, 0, 0);
        __syncthreads();   // compiler emits s_waitcnt vmcnt(0) before s_barrier

        bf16x8 af[4], bfr[4];
#pragma unroll
        for (int mi = 0; mi < 4; ++mi)
            af[mi] = *(const bf16x8*)(As + (wr * 64 + mi * 16 + lane16) * BK + quad * 8);
#pragma unroll
        for (int ni = 0; ni < 4; ++ni)
            bfr[ni] = *(const bf16x8*)(Bs + (wc * 64 + ni * 16 + lane16) * BK + quad * 8);
#pragma unroll
        for (int mi = 0; mi < 4; ++mi)
#pragma unroll
            for (int ni = 0; ni < 4; ++ni)
                acc[mi][ni] = __builtin_amdgcn_mfma_f32_16x16x32_bf16(
                    af[mi], bfr[ni], acc[mi][ni], 0, 0, 0);
    }

    // Epilogue: C/D layout col=lane&15, row=quad*4+reg
    const int rowG = rowBase + wr * 64;
#pragma unroll
    for (int mi = 0; mi < 4; ++mi) {
#pragma unroll
        for (int r = 0; r < 4; ++r) {
            float s = 0.f;
#pragma unroll
            for (int ni = 0; ni < 4; ++ni) {
                int col = colBase + wc * 64 + ni * 16 + lane16;
                float v = acc[mi][ni][r] + b2[col];
                s += tanhf(v) * W3[col];
            }
#pragma unroll
            for (int off = 1; off < 16; off <<= 1) s += __shfl_xor(s, off, 64);
            if (lane16 == 0)
                atomicAdd(&rowsum[rowG + mi * 16 + quad * 4 + r], s);
        }
    }
}

// ---------------- Kernel 4: u = 3*tanh(rowsum + b3) ----------------
__global__ void finish_u(const float* __restrict__ rowsum, const float* __restrict__ b3,
                         float* __restrict__ u) {
    int i = blockIdx.x * 256 + threadIdx.x;     // 16 blocks cover 4096
    u[i] = 3.0f * tanhf(rowsum[i] + b3[0]);
}

// ---------------- Kernel 5: quadratic B-spline gather ----------------
__global__ void spline_kernel(const float2* __restrict__ pts, const float* __restrict__ u,
                              float* __restrict__ out, int n) {
    __shared__ float us[4096];
    for (int i = threadIdx.x; i < 4096; i += blockDim.x) us[i] = u[i];
    __syncthreads();
    int stride = gridDim.x * blockDim.x;
    for (int idx = blockIdx.x * blockDim.x + threadIdx.x; idx < n; idx += stride) {
        float2 pt = pts[idx];
        float x = (pt.x + 1.0f) * 0.5f;
        float y = pt.y;
        float px = x * 62.0f, py = y * 62.0f;
        float fx = floorf(px), fy = floorf(py);
        int posx = min((int)fx + 1, 62);
        int posy = min((int)fy + 1, 62);
        float tx = px - fx, ty = py - fy;     // == mod(p,1) for p>=0
        float bx0 = 0.5f * (1.f - tx) * (1.f - tx);
        float bx1 = -tx * tx + tx + 0.5f;
        float bx2 = 0.5f * tx * tx;
        float by0 = 0.5f * (1.f - ty) * (1.f - ty);
        float by1 = -ty * ty + ty + 0.5f;
        float by2 = 0.5f * ty * ty;
        int ix = posx - 1, iy = posy - 1;
        const float* r0 = &us[ix * 64 + iy];
        const float* r1 = r0 + 64;
        const float* r2 = r1 + 64;
        float s0 = r0[0] * by0 + r0[1] * by1 + r0[2] * by2;
        float s1 = r1[0] * by0 + r1[1] * by1 + r1[2] * by2;
        float s2 = r2[0] * by0 + r2[1] * by1 + r2[2] * by2;
        out[idx] = bx0 * s0 + bx1 * s1 + bx2 * s2;
    }
}

extern "C" void kernel_launch(void* const* d_in, const int* in_sizes, int n_in,
                              void* d_out, int out_size, void* d_ws, size_t ws_size,
                              hipStream_t stream) {
    const float* points = (const float*)d_in[0];
    const float* W1 = (const float*)d_in[1];
    const float* b1 = (const float*)d_in[2];
    const float* W2 = (const float*)d_in[3];
    const float* b2 = (const float*)d_in[4];
    const float* W3 = (const float*)d_in[5];
    const float* b3 = (const float*)d_in[6];
    float* out = (float*)d_out;

    char* ws = (char*)d_ws;
    unsigned short* hbf = (unsigned short*)ws;                        // 16777216 B
    unsigned short* w2t = (unsigned short*)(ws + 16777216);           //  8388608 B
    float* rowsum = (float*)(ws + 25165824);                          //    16384 B
    float* u      = (float*)(ws + 25165824 + 16384);                  //    16384 B

    hipMemsetAsync(rowsum, 0, IN_DIM * sizeof(float), stream);
    prep_h<<<8192, 256, 0, stream>>>(W1, b1, hbf);
    prep_w2t<<<dim3(32, 32), 256, 0, stream>>>(W2, w2t);
    gemm_fused<<<dim3(H_DIM / 128, IN_DIM / 128), 256, 0, stream>>>(hbf, w2t, b2, W3, rowsum);
    finish_u<<<16, 256, 0, stream>>>(rowsum, b3, u);
    spline_kernel<<<1024, 256, 0, stream>>>((const float2*)points, u, out, NPTS);
}